// Round 6
// baseline (269.659 us; speedup 1.0000x reference)
//
#include <hip/hip_runtime.h>
#include <stdint.h>

// Radius-graph edge list, B=4, N=2048, cutoff 5.0.
// Output [2, B*P] int32: compacted valid edges (ascending flat index), -1 pad.
// Single-pass decoupled-lookback compaction (2 dispatches):
//   init  : <<<1,1>>> zero the vbid ticket (ws is poisoned 0xAA every launch).
//   radius: per-block: grab vbid ticket -> fill own out-slice with -1 ->
//           hot loop (incremental row-walk, 8-bit hit mask) -> block count ->
//           publish partial flag (release,agent) -> wave-parallel lookback
//           over predecessor flags -> publish inclusive -> write edges
//           DIRECTLY to final positions.
// Safety: flag = (val<<8)|status, status 1=partial/3=inclusive; poison byte
// 0xAA reads as not-ready so flags need no init. Ticket ordering means a
// block only spins on blocks that already started (rocPRIM scheme). Edges of
// chunk v land only in slices of chunks <= v, whose -1 fills are ordered
// before our edge writes by the release->acquire flag chain.

namespace {
constexpr int kB = 4;
constexpr int kN = 2048;
constexpr int kP = kN * (kN - 1) / 2;              // 2096128
constexpr long long kTotal = (long long)kB * kP;   // 8384512
constexpr int kBlock = 256;
constexpr int kItems = 8;
constexpr int kChunk = kBlock * kItems;            // 2048
constexpr int kNBlk = (int)(kTotal / kChunk);      // 4094 (exact, no tail)
constexpr float kCut2 = 25.0f;                     // 5.0^2
}  // namespace

// p in [0,P) -> (i,j), i<j, triu row-major. Closed-form sqrt guess + exact
// integer fixup. C(i) = i*(4095-i)/2. disc < 2^24 so float sqrt is tight.
__device__ __forceinline__ void decode_pair(int p, int& i, int& j) {
  float t = sqrtf((float)(16769025 - 8 * p));
  int ii = (int)((4095.0f - t) * 0.5f);
  ii = ii < 0 ? 0 : (ii > kN - 2 ? kN - 2 : ii);
  while (ii > 0 && (ii * (4095 - ii)) / 2 > p) --ii;
  while (ii < kN - 2 && ((ii + 1) * (4094 - ii)) / 2 <= p) ++ii;
  i = ii;
  j = ii + 1 + (p - (ii * (4095 - ii)) / 2);
}

__global__ void init_kernel(uint32_t* __restrict__ ticket) { *ticket = 0u; }

__global__ __launch_bounds__(kBlock) void radius_kernel(const float* __restrict__ x,
                                                        uint32_t* __restrict__ flags,
                                                        uint32_t* __restrict__ ticket,
                                                        int* __restrict__ out) {
  const int t = threadIdx.x;
  const int wave = t >> 6, lane = t & 63;
  __shared__ uint32_t s_vbid, s_run, s_exc, slot[32];

  if (t == 0) s_vbid = atomicAdd(ticket, 1u);  // device-scope; scheduling order
  if (t < 32) slot[t] = 0;
  __syncthreads();
  const int bid = (int)s_vbid;
  const int base = bid * kChunk;

  // Fill this chunk's slice of both output rows with -1 (2048 ints each).
  {
    const int4 m1 = make_int4(-1, -1, -1, -1);
    int4* o0 = (int4*)out + (base >> 2);
    int4* o1 = (int4*)(out + kTotal) + (base >> 2);
    o0[t] = m1;
    o0[t + kBlock] = m1;
    o1[t] = m1;
    o1[t + kBlock] = m1;
  }

  // One sqrt-decode per thread per block, then incremental row-walk (+256/item).
  int b = base / kP;
  int p = base - b * kP + t;
  if (p >= kP) { p -= kP; ++b; }
  int i, j;
  decode_pair(p, i, j);
  int ib = b * kN;  // point-index base of batch b

  const float3* __restrict__ x3 = (const float3*)x;
  float3 pi = x3[ib + i];

  uint32_t hits = 0;  // bit k = item k is an edge
#pragma unroll
  for (int k = 0; k < kItems; ++k) {
    float3 pj = x3[ib + j];
    float dx = pi.x - pj.x, dy = pi.y - pj.y, dz = pi.z - pj.z;
    if (dx * dx + dy * dy + dz * dz <= kCut2) hits |= (1u << k);
    if (k < kItems - 1) {
      j += kBlock;
      if (j >= kN) {  // ~20% of items, mostly wave-coherent
        do {
          int ex = j - kN;
          ++i;
          if (i >= kN - 1) { i = 0; ib += kN; }
          j = i + 1 + ex;
        } while (j >= kN);
        pi = x3[ib + i];
      }
    }
  }

  const bool waveany = (__ballot(hits != 0) != 0ULL);  // wave-uniform
  if (waveany) {
#pragma unroll
    for (int k = 0; k < kItems; ++k) {
      unsigned long long m = __ballot((hits >> k) & 1u);
      if (m != 0ULL && lane == 0) slot[k * 4 + wave] = (uint32_t)__popcll(m);
    }
  }
  __syncthreads();
  if (t < 32) {  // exclusive scan of 32 (item,wave) counts; stash block total
    uint32_t v = slot[t];
    uint32_t run = v;
    for (int off = 1; off < 32; off <<= 1) {
      uint32_t u = __shfl_up(run, off, 64);
      if (t >= off) run += u;
    }
    slot[t] = run - v;
    if (t == 31) s_run = run;
  }
  __syncthreads();
  const uint32_t run = s_run;

  // Publish partial (or inclusive for vbid 0). Release orders the -1 fill
  // (pre-barrier stores) before the flag for any acquirer.
  if (t == 0) {
    uint32_t f = (run << 8) | (bid == 0 ? 3u : 1u);
    __hip_atomic_store(&flags[bid], f, __ATOMIC_RELEASE, __HIP_MEMORY_SCOPE_AGENT);
    if (bid == 0) s_exc = 0;
  }

  if (bid != 0 && t < 64) {  // wave-parallel lookback, 64 predecessors/round
    uint32_t exc = 0;
    int look = bid - 1 - lane;
    bool fin = false;
    while (!fin) {
      uint32_t f = 3u;  // out-of-range => inclusive 0
      if (look >= 0) {
        do {
          f = __hip_atomic_load(&flags[look], __ATOMIC_RELAXED,
                                __HIP_MEMORY_SCOPE_AGENT);
        } while (((f & 0xFFu) != 1u) && ((f & 0xFFu) != 3u));
      }
      const bool incl = (f & 0xFFu) == 3u;
      unsigned long long im = __ballot(incl);
      uint32_t val = f >> 8;
      uint32_t contrib;
      if (im != 0ULL) {  // nearest inclusive predecessor = lowest set lane
        int L = (int)__builtin_ctzll(im);
        contrib = (lane <= L) ? val : 0u;
        fin = true;
      } else {
        contrib = val;  // all partials: take them and keep walking back
      }
      for (int o = 32; o > 0; o >>= 1) contrib += __shfl_down(contrib, o, 64);
      contrib = __shfl(contrib, 0, 64);
      exc += contrib;
      look -= 64;
    }
    __builtin_amdgcn_fence(__ATOMIC_ACQUIRE, "agent");  // one invalidate, post-spin
    if (lane == 0) {
      __hip_atomic_store(&flags[bid], ((exc + run) << 8) | 3u, __ATOMIC_RELEASE,
                         __HIP_MEMORY_SCOPE_AGENT);
      s_exc = exc;
    }
  }
  __syncthreads();
  const uint32_t exc = s_exc;

  // Write edges directly to final compacted positions.
  if (waveany) {
#pragma unroll
    for (int k = 0; k < kItems; ++k) {
      bool f = (hits >> k) & 1u;
      unsigned long long m = __ballot(f);
      if (m != 0ULL && f) {  // rare: ~3 hits per block total
        int pf = base + k * kBlock + t;
        int hb = pf / kP;
        int hp = pf - hb * kP;
        int hi, hj;
        decode_pair(hp, hi, hj);
        uint32_t pos = exc + slot[k * 4 + wave] +
                       (uint32_t)__popcll(m & ((1ULL << lane) - 1ULL));
        out[pos] = hb * kN + hi;
        out[(size_t)kTotal + pos] = hb * kN + hj;
      }
    }
  }
}

extern "C" void kernel_launch(void* const* d_in, const int* in_sizes, int n_in,
                              void* d_out, int out_size, void* d_ws, size_t ws_size,
                              hipStream_t stream) {
  const float* x = (const float*)d_in[0];
  int* out = (int*)d_out;
  uint32_t* flags = (uint32_t*)d_ws;                  // [4094], poison-safe
  uint32_t* ticket = flags + 4096;                    // [1], zeroed by init

  hipLaunchKernelGGL(init_kernel, dim3(1), dim3(1), 0, stream, ticket);
  hipLaunchKernelGGL(radius_kernel, dim3(kNBlk), dim3(kBlock), 0, stream, x, flags,
                     ticket, out);
}

// Round 7
// 92.219 us; speedup vs baseline: 2.9241x; 2.9241x over previous
//
#include <hip/hip_runtime.h>
#include <stdint.h>

// Radius-graph edge list, B=4, N=2048, cutoff 5.0.
// Output [2, B*P] int32: compacted valid edges (ascending flat index), -1 pad.
// Pipeline (2 kernels, NO inter-block spin — round-6's lookback cross-XCD
// polling was a 2.3x disaster, VALUBusy 6.7%):
//   pass1  : fill own out-slice with -1; incremental (b,i,j) row-walk with
//            cached pi; hot loop accumulates an 8-bit hit mask/thread;
//            epilogue: ballots + 32-slot scan + count + stash (kCap=128).
//   scatter: each block independently uint4-loads ALL 4096 counts (16 KB,
//            L2-hot) and block-reduces counts[idx<bid] to get its own global
//            offset — no scan dispatch, no inter-block communication. Then
//            copies stash to final positions (recompute fallback if
//            count > kCap; deterministic + exact).

namespace {
constexpr int kB = 4;
constexpr int kN = 2048;
constexpr int kP = kN * (kN - 1) / 2;              // 2096128
constexpr long long kTotal = (long long)kB * kP;   // 8384512
constexpr int kBlock = 256;
constexpr int kItems = 8;
constexpr int kChunk = kBlock * kItems;            // 2048
constexpr int kNBlk = (int)(kTotal / kChunk);      // 4094 (exact, no tail)
constexpr float kCut2 = 25.0f;                     // 5.0^2
constexpr int kCap = 128;                          // stash slots per block
}  // namespace

// p in [0,P) -> (i,j), i<j, triu row-major. Closed-form sqrt guess + exact
// integer fixup. C(i) = i*(4095-i)/2. disc < 2^24 so float sqrt is tight.
__device__ __forceinline__ void decode_pair(int p, int& i, int& j) {
  float t = sqrtf((float)(16769025 - 8 * p));
  int ii = (int)((4095.0f - t) * 0.5f);
  ii = ii < 0 ? 0 : (ii > kN - 2 ? kN - 2 : ii);
  while (ii > 0 && (ii * (4095 - ii)) / 2 > p) --ii;
  while (ii < kN - 2 && ((ii + 1) * (4094 - ii)) / 2 <= p) ++ii;
  i = ii;
  j = ii + 1 + (p - (ii * (4095 - ii)) / 2);
}

__device__ __forceinline__ bool pair_test(const float* __restrict__ x, int b, int p,
                                          int& gi, int& gj) {
  int i, j;
  decode_pair(p, i, j);
  const float* xb = x + (size_t)b * kN * 3;
  float dx = xb[3 * i + 0] - xb[3 * j + 0];
  float dy = xb[3 * i + 1] - xb[3 * j + 1];
  float dz = xb[3 * i + 2] - xb[3 * j + 2];
  gi = b * kN + i;
  gj = b * kN + j;
  return dx * dx + dy * dy + dz * dz <= kCut2;
}

__global__ __launch_bounds__(kBlock) void pass1_kernel(const float* __restrict__ x,
                                                       uint32_t* __restrict__ counts,
                                                       int2* __restrict__ stash,
                                                       int* __restrict__ out) {
  const int t = threadIdx.x;
  const int wave = t >> 6, lane = t & 63;
  const int bid = blockIdx.x;
  const int base = bid * kChunk;

  // Fill this block's slice of both output rows with -1 (2048 ints each).
  {
    const int4 m1 = make_int4(-1, -1, -1, -1);
    int4* o0 = (int4*)out + (base >> 2);
    int4* o1 = (int4*)(out + kTotal) + (base >> 2);
    o0[t] = m1;
    o0[t + kBlock] = m1;
    o1[t] = m1;
    o1[t + kBlock] = m1;
  }
  if (bid == 0 && t < 2) counts[kNBlk + t] = 0;  // pad so scatter can uint4-load

  // One sqrt-decode per thread per block, then incremental row-walk (+256/item).
  int b = base / kP;
  int p = base - b * kP + t;
  if (p >= kP) { p -= kP; ++b; }
  int i, j;
  decode_pair(p, i, j);
  int ib = b * kN;  // point-index base of batch b

  const float3* __restrict__ x3 = (const float3*)x;
  float3 pi = x3[ib + i];

  uint32_t hits = 0;  // bit k = item k is an edge
#pragma unroll
  for (int k = 0; k < kItems; ++k) {
    float3 pj = x3[ib + j];
    float dx = pi.x - pj.x, dy = pi.y - pj.y, dz = pi.z - pj.z;
    if (dx * dx + dy * dy + dz * dz <= kCut2) hits |= (1u << k);
    if (k < kItems - 1) {
      j += kBlock;
      if (j >= kN) {  // ~20% of items, mostly wave-coherent
        do {
          int ex = j - kN;
          ++i;
          if (i >= kN - 1) { i = 0; ib += kN; }
          j = i + 1 + ex;
        } while (j >= kN);
        pi = x3[ib + i];
      }
    }
  }

  __shared__ uint32_t slot[32];
  if (t < 32) slot[t] = 0;
  __syncthreads();

  const bool waveany = (__ballot(hits != 0) != 0ULL);  // wave-uniform
  if (waveany) {
#pragma unroll
    for (int k = 0; k < kItems; ++k) {
      unsigned long long m = __ballot((hits >> k) & 1u);
      if (m != 0ULL && lane == 0) slot[k * 4 + wave] = (uint32_t)__popcll(m);
    }
  }
  __syncthreads();
  if (t < 32) {  // exclusive scan of 32 (item,wave) counts; write block total
    uint32_t v = slot[t];
    uint32_t run = v;
    for (int off = 1; off < 32; off <<= 1) {
      uint32_t u = __shfl_up(run, off, 64);
      if (t >= off) run += u;
    }
    slot[t] = run - v;
    if (t == 31) counts[bid] = run;
  }
  __syncthreads();
  if (waveany) {
#pragma unroll
    for (int k = 0; k < kItems; ++k) {
      bool f = (hits >> k) & 1u;
      unsigned long long m = __ballot(f);
      if (m != 0ULL && f) {  // rare: ~3 hits per block total
        int pf = base + k * kBlock + t;
        int hb = pf / kP;
        int hp = pf - hb * kP;
        int hi, hj;
        decode_pair(hp, hi, hj);
        uint32_t pos = slot[k * 4 + wave] +
                       (uint32_t)__popcll(m & ((1ULL << lane) - 1ULL));
        if (pos < (uint32_t)kCap)
          stash[(size_t)bid * kCap + pos] = make_int2(hb * kN + hi, hb * kN + hj);
      }
    }
  }
}

__global__ __launch_bounds__(kBlock) void scatter_kernel(const float* __restrict__ x,
                                                         const uint32_t* __restrict__ counts,
                                                         const int2* __restrict__ stash,
                                                         int* __restrict__ out) {
  const int bid = blockIdx.x;
  const int t = threadIdx.x;

  // Self-service prefix: offset = sum(counts[idx < bid]), from 16 KB L2-hot.
  const uint4* c4 = (const uint4*)counts;  // [4096] incl. zero pad
  uint32_t part = 0;
#pragma unroll
  for (int q = 0; q < 4; ++q) {
    uint4 v = c4[t * 4 + q];
    int i0 = t * 16 + q * 4;
    part += (i0 + 0 < bid) ? v.x : 0u;
    part += (i0 + 1 < bid) ? v.y : 0u;
    part += (i0 + 2 < bid) ? v.z : 0u;
    part += (i0 + 3 < bid) ? v.w : 0u;
  }
  for (int o = 32; o > 0; o >>= 1) part += __shfl_down(part, o, 64);
  __shared__ uint32_t wred[4];
  if ((t & 63) == 0) wred[t >> 6] = part;
  __syncthreads();
  if (t == 0) wred[0] = wred[0] + wred[1] + wred[2] + wred[3];
  __syncthreads();
  const uint32_t off = wred[0];
  const uint32_t cnt = counts[bid];
  if (cnt == 0) return;

  if (cnt <= (uint32_t)kCap) {
    for (uint32_t e = t; e < cnt; e += kBlock) {
      int2 v = stash[(size_t)bid * kCap + e];
      out[off + e] = v.x;
      out[(size_t)kTotal + off + e] = v.y;
    }
    return;
  }
  // Overflow fallback (count > kCap): recompute this block's edges with
  // ballot ranks and write directly. Deterministic + exact.
  const int wave = t >> 6, lane = t & 63;
  const int base = bid * kChunk;
  const int bb0 = base / kP;
  const int p0 = base - bb0 * kP;
  __shared__ uint32_t slot[kItems * 4];
  unsigned long long masks[kItems];
  int gi[kItems], gj[kItems];
  bool fl[kItems];
  for (int k = 0; k < kItems; ++k) {
    int o = k * kBlock + t;
    int b = bb0, p = p0 + o;
    if (p >= kP) { p -= kP; ++b; }
    fl[k] = pair_test(x, b, p, gi[k], gj[k]);
    masks[k] = __ballot(fl[k]);
    if (lane == 0) slot[k * 4 + wave] = (uint32_t)__popcll(masks[k]);
  }
  __syncthreads();
  if (t == 0) {
    uint32_t run = 0;
    for (int s = 0; s < kItems * 4; ++s) {
      uint32_t c = slot[s];
      slot[s] = run;
      run += c;
    }
  }
  __syncthreads();
  for (int k = 0; k < kItems; ++k) {
    if (fl[k]) {
      uint32_t pos = off + slot[k * 4 + wave] +
                     (uint32_t)__popcll(masks[k] & ((1ULL << lane) - 1ULL));
      out[pos] = gi[k];
      out[(size_t)kTotal + pos] = gj[k];
    }
  }
}

extern "C" void kernel_launch(void* const* d_in, const int* in_sizes, int n_in,
                              void* d_out, int out_size, void* d_ws, size_t ws_size,
                              hipStream_t stream) {
  const float* x = (const float*)d_in[0];
  int* out = (int*)d_out;
  uint32_t* counts = (uint32_t*)d_ws;                 // [4096] (2 pad)
  int2* stash = (int2*)(counts + 4096);               // [4094 * kCap] ~4.2 MB

  hipLaunchKernelGGL(pass1_kernel, dim3(kNBlk), dim3(kBlock), 0, stream, x, counts,
                     stash, out);
  hipLaunchKernelGGL(scatter_kernel, dim3(kNBlk), dim3(kBlock), 0, stream, x, counts,
                     stash, out);
}